// Round 1
// baseline (621.226 us; speedup 1.0000x reference)
//
#include <hip/hip_runtime.h>
#include <stdint.h>

// Problem constants (match the reference).
#define B 256
#define K 64
#define L 32
#define SENTINEL 32
#define NUM_SLOTS 100000
#define HALF 64

// Packed per-(batch,node) table: 2 bytes per slot.
//   low byte  = min position of node in src walks (init SENTINEL=0x20)
//   high byte = min position of node in tgt walks (init SENTINEL=0x20)
// Total: 256 * 100000 * 2 = 51,200,000 bytes in d_ws.
static constexpr size_t TABLE_BYTES = (size_t)B * NUM_SLOTS * 2;

// ---------------------------------------------------------------------------
// Kernel 1: scatter-min of walk positions into the packed byte table.
// 2*B*K*L = 1,048,576 threads. tid layout: [which(1)][b(8)][k(6)][l(5)]
// ---------------------------------------------------------------------------
__global__ void wpe_scatter_kernel(const int* __restrict__ src_walks,
                                   const int* __restrict__ tgt_walks,
                                   const int* __restrict__ src_lens,
                                   const int* __restrict__ tgt_lens,
                                   unsigned int* __restrict__ table_words) {
  unsigned int tid = blockIdx.x * blockDim.x + threadIdx.x;
  unsigned int which = tid >> 19;          // 0 = src, 1 = tgt
  unsigned int r = tid & 0x7FFFFu;         // flat (b,k,l), 2^19 entries
  unsigned int b = r >> 11;                // K*L = 2048 = 2^11
  unsigned int k = (r >> 5) & 63u;
  unsigned int l = r & 31u;

  const int* walks = which ? tgt_walks : src_walks;
  const int* lens  = which ? tgt_lens  : src_lens;

  int node = walks[r];
  int len  = lens[b * K + k];

  // Invalid entries scatter SENTINEL in the reference -> no-op vs SENTINEL init.
  if ((int)l < len && node != 0) {
    unsigned int byteIdx = (b * (unsigned)NUM_SLOTS + (unsigned)node) * 2u + which;
    unsigned int* addr = table_words + (byteIdx >> 2);
    unsigned int shift = (byteIdx & 3u) * 8u;
    unsigned int mask  = 0xFFu << shift;
    unsigned int val   = l;

    unsigned int old = *(volatile unsigned int*)addr;
    while (true) {
      unsigned int cur = (old >> shift) & 0xFFu;
      if (val >= cur) break;  // not improving the min -> done
      unsigned int neu = (old & ~mask) | (val << shift);
      unsigned int prev = atomicCAS(addr, old, neu);
      if (prev == old) break;
      old = prev;
    }
  }
}

// ---------------------------------------------------------------------------
// Kernel 2: gather positions, look up embeddings, write output.
// One float4 per thread; 32 threads per 128-float output row.
// Row layout matches output: rows [0, 2^19) = src_pos, [2^19, 2^20) = tgt_pos,
// row r within each = b*2048 + k*32 + l (row-major B,K,L).
// ---------------------------------------------------------------------------
__global__ void wpe_gather_kernel(const int* __restrict__ src_walks,
                                  const int* __restrict__ tgt_walks,
                                  const int* __restrict__ src_lens,
                                  const int* __restrict__ tgt_lens,
                                  const float* __restrict__ own_emb,
                                  const float* __restrict__ cross_emb,
                                  const unsigned short* __restrict__ table,
                                  float4* __restrict__ out) {
  unsigned int tid = blockIdx.x * blockDim.x + threadIdx.x;  // < 2^25
  unsigned int row = tid >> 5;
  unsigned int c   = tid & 31u;            // which float4 within the 128-float row

  unsigned int which = row >> 19;
  unsigned int r = row & 0x7FFFFu;
  unsigned int b = r >> 11;
  unsigned int k = (r >> 5) & 63u;
  unsigned int l = r & 31u;

  const int* walks = which ? tgt_walks : src_walks;
  const int* lens  = which ? tgt_lens  : src_lens;

  int node = walks[r];
  int len  = lens[b * K + k];

  float4 v;
  if ((int)l < len && node != 0) {
    unsigned int packed = table[b * (unsigned)NUM_SLOTS + (unsigned)node];
    unsigned int psrc = packed & 0xFFu;    // min pos in src walks (or SENTINEL)
    unsigned int ptgt = packed >> 8;       // min pos in tgt walks (or SENTINEL)
    unsigned int pown   = which ? ptgt : psrc;
    unsigned int pcross = which ? psrc : ptgt;
    const float4* emb = (c < 16u)
        ? (const float4*)(own_emb   + (size_t)pown   * HALF)
        : (const float4*)(cross_emb + (size_t)pcross * HALF);
    v = emb[c & 15u];
  } else {
    v = make_float4(0.f, 0.f, 0.f, 0.f);
  }
  out[tid] = v;
}

// ---------------------------------------------------------------------------
extern "C" void kernel_launch(void* const* d_in, const int* in_sizes, int n_in,
                              void* d_out, int out_size, void* d_ws, size_t ws_size,
                              hipStream_t stream) {
  const int*   src_walks = (const int*)d_in[0];
  const int*   tgt_walks = (const int*)d_in[1];
  const int*   src_lens  = (const int*)d_in[2];
  const int*   tgt_lens  = (const int*)d_in[3];
  const float* own_emb   = (const float*)d_in[4];
  const float* cross_emb = (const float*)d_in[5];

  // Step 1: init packed table to SENTINEL (=32=0x20) in every byte.
  hipMemsetAsync(d_ws, 0x20, TABLE_BYTES, stream);

  // Step 2: scatter-min walk positions.
  {
    const unsigned int total = 2u * B * K * L;  // 1,048,576
    wpe_scatter_kernel<<<total / 256, 256, 0, stream>>>(
        src_walks, tgt_walks, src_lens, tgt_lens, (unsigned int*)d_ws);
  }

  // Step 3: gather + embed + write.
  {
    const unsigned int total = 2u * B * K * L * 32u;  // 33,554,432 float4s
    wpe_gather_kernel<<<total / 256, 256, 0, stream>>>(
        src_walks, tgt_walks, src_lens, tgt_lens, own_emb, cross_emb,
        (const unsigned short*)d_ws, (float4*)d_out);
  }
}